// Round 6
// baseline (274.019 us; speedup 1.0000x reference)
//
#include <hip/hip_runtime.h>
#include <cmath>

typedef _Float16 half_t;
typedef _Float16 half8 __attribute__((ext_vector_type(8)));
typedef _Float16 half4v __attribute__((ext_vector_type(4)));
typedef float float4v __attribute__((ext_vector_type(4)));

#define LOG2E 1.44269504088896340736f

#define GLDS16(g, l)                                                                   \
    __builtin_amdgcn_global_load_lds((const __attribute__((address_space(1))) void*)(g), \
                                     (__attribute__((address_space(3))) void*)(l), 16, 0, 0)

// raw barriers: no compiler-inserted vmcnt(0) drain (the __syncthreads trap)
#define BAR_LGKM() __asm__ volatile("s_waitcnt lgkmcnt(0)\n\ts_barrier" ::: "memory")
#define BAR_VM(n)  __asm__ volatile("s_waitcnt vmcnt(" #n ")\n\ts_barrier" ::: "memory")

// ---------------- cast fp32 -> fp16 ----------------
__global__ void cast_f32_f16(const float* __restrict__ in, half_t* __restrict__ out, int n) {
    int i = (blockIdx.x * blockDim.x + threadIdx.x) * 4;
    if (i >= n) return;
    float4 v = *(const float4*)(in + i);
    half4v o;
    o[0] = (half_t)v.x; o[1] = (half_t)v.y; o[2] = (half_t)v.z; o[3] = (half_t)v.w;
    *(half4v*)(out + i) = o;
}

// ---------------- transpose + cast: in fp32 [R][C] -> out fp16 [C][R] ----------------
__global__ void transpose_cast(const float* __restrict__ in, half_t* __restrict__ out, int R, int C) {
    __shared__ float tile[32][33];
    int c0 = blockIdx.x * 32, r0 = blockIdx.y * 32;
    int tx = threadIdx.x, ty = threadIdx.y; // block (32,8)
    for (int p = 0; p < 4; p++) {
        int r = r0 + ty + p * 8;
        tile[ty + p * 8][tx] = in[(size_t)r * C + c0 + tx];
    }
    __syncthreads();
    for (int p = 0; p < 4; p++) {
        int c = c0 + ty + p * 8;
        out[(size_t)c * R + r0 + tx] = (half_t)tile[tx][ty + p * 8];
    }
}

// =====================================================================================
// QKV GEMM: 128x256 tile, BK=64, 8 waves (2M x 4N, per-wave 64x64), grid 768 = EXACTLY
// 3 rounds of 256 CUs (the r5 lesson: 384 blocks @1/CU = 0.75 packing was 25% of wall).
// 2 phases/K-tile (one K-half each, 16 MFMA), reads pipelined one phase ahead (r5
// structure), stages split BY K-HALF so each 3-GLDS group commits independently:
//   LDS: As[2][2][128*32] + Bs[2][2][256*32] = 96 KiB, [buf][kk][row][32] blocks.
//   p0(T): lgkm0 | read kk1(T)->af1,b1 | stage kk1(T+1)->nbuf (3 GLDS) |
//          MFMA16(af0,b0) | vmcnt(3) bar
//   p1(T): lgkm0 | read kk0(T+1)->af0,b0 | stage kk0(T+2)->buf (3 GLDS) |
//          MFMA16(af1,b1) | vmcnt(3) bar
//   Ledger: entering any phase <=3 outstanding; phase issues 3; vmcnt(3) at end
//   guarantees the older group (needed next phase) landed. Restage of a region is
//   always >=2 phases after its last read (intervening lgkm+barrier = cross-wave safe).
//   Tail: vmcnt(0) when a phase issues no stage.
// Swizzle (same verified mod-4 rotate for BOTH A and B, rows are 64B):
//   stored chunk pos c' = (c + (row>>1)) & 3; source bc = ((t&3)-(t>>3))&3;
//   read posq = (quad + (lrow>>1)) & 3 (row terms uniform: wm/wn*64, mi/ni*16 == 0 mod 4
//   after >>1... verified 0 conflicts in r2/r5).
// Registers: acc 64 + af0/af1 32 + b0/b1 32 ~= 128 + addr -> ~160, no spill at 2 w/SIMD.
// =====================================================================================
__global__ __launch_bounds__(512, 2) void gemm_qkv(
    const half_t* __restrict__ A,   // [M][K] = xh
    const half_t* __restrict__ Bt,  // [N][K] = Wqt
    const float* __restrict__ bias, // [N]
    const float* __restrict__ wq, const float* __restrict__ wk,
    half_t* __restrict__ Qh, half_t* __restrict__ Kh, half_t* __restrict__ Vt,
    int M, int N, int K)
{
    __shared__ __align__(16) half_t As[2][2][128 * 32];  // [buf][khalf][row*32+chunk*8]
    __shared__ __align__(16) half_t Bs[2][2][256 * 32];  // [buf][khalf]

    int t = threadIdx.x;
    int lane = t & 63, w = t >> 6;
    int lrow = lane & 15, quad = lane >> 4;
    int wm = w >> 2, wn = w & 3;           // 2M x 4N

    // XCD-aware swizzle (grid 768 % 8 == 0 -> simple form is bijective)
    int cpx = gridDim.x >> 3;
    int bid = blockIdx.x;
    int wg = (bid & 7) * cpx + (bid >> 3);
    int nbn = N >> 8;                      // 12
    int mb = wg / nbn, nb = wg % nbn;
    int m0 = mb << 7, n0 = nb << 8;        // 128-row x 256-col tiles

    // ---- staging source pointers (source pre-swizzled: bc inverse of (c+(row>>1))&3) --
    int sr = t >> 2;                       // staging row 0..127
    int bc = ((t & 3) - (t >> 3)) & 3;
    const half_t* gAbase = A  + (size_t)(m0 + sr) * K + bc * 8;
    const half_t* gBbase = Bt + (size_t)(n0 + sr) * K + bc * 8;

    auto stageA = [&](int buf, int kk, int T) {        // 1 GLDS = 128 x 32
        GLDS16(gAbase + T * 64 + kk * 32, &As[buf][kk][w * 512]);
    };
    auto stageB = [&](int buf, int kk, int T) {        // 2 GLDS = 256 x 32
        const half_t* s = gBbase + T * 64 + kk * 32;
        GLDS16(s,                   &Bs[buf][kk][w * 512]);
        GLDS16(s + (size_t)128 * K, &Bs[buf][kk][4096 + w * 512]);
    };

    // ---- ds_read offsets ----
    int posq = (quad + (lrow >> 1)) & 3;
    int aoffs = (wm * 64 + lrow) * 32 + posq * 8;
    int boffs = (wn * 64 + lrow) * 32 + posq * 8;

    half8 af0[4], af1[4];                  // A frags (kk-alternating)
    half8 b0[4], b1[4];                    // B frags
    float4v acc[4][4] = {};                // [mi][ni], 64x64 per-wave output

    auto loadA = [&](int buf, int kk, half8 (&dst)[4]) {
        #pragma unroll
        for (int mi = 0; mi < 4; mi++)
            dst[mi] = *(const half8*)(&As[buf][kk][aoffs + mi * 512]);
    };
    auto loadB = [&](int buf, int kk, half8 (&dst)[4]) {
        #pragma unroll
        for (int ni = 0; ni < 4; ni++)
            dst[ni] = *(const half8*)(&Bs[buf][kk][boffs + ni * 512]);
    };

#define MFMA16(AF, BF)                                                            \
    do { _Pragma("unroll")                                                        \
        for (int mi = 0; mi < 4; mi++) { _Pragma("unroll")                        \
            for (int ni = 0; ni < 4; ni++)                                        \
                acc[mi][ni] = __builtin_amdgcn_mfma_f32_16x16x32_f16(             \
                    AF[mi], BF[ni], acc[mi][ni], 0, 0, 0);                        \
        } } while (0)

#define PH_TOP()                                                   \
    do {                                                           \
        __asm__ volatile("s_waitcnt lgkmcnt(0)" ::: "memory");     \
        __builtin_amdgcn_sched_barrier(0);                         \
    } while (0)
#define PH_BOT(STG)                                                               \
    do {                                                                          \
        __builtin_amdgcn_sched_barrier(0);                                        \
        if (STG) { __asm__ volatile("s_waitcnt vmcnt(3)" ::: "memory"); }         \
        else     { __asm__ volatile("s_waitcnt vmcnt(0)" ::: "memory"); }         \
        __asm__ volatile("s_barrier" ::: "memory");                               \
    } while (0)

    int nk = K >> 6;   // 16 K-tiles of 64

    // ---- prologue: stage kk0(0), kk1(0), kk0(1) [9 GLDS], commit tile0, read kk0(0) --
    stageA(0, 0, 0); stageB(0, 0, 0);
    stageA(0, 1, 0); stageB(0, 1, 0);
    stageA(1, 0, 1); stageB(1, 0, 1);
    __asm__ volatile("s_waitcnt vmcnt(3)" ::: "memory");   // tile0 both halves landed
    __asm__ volatile("s_barrier" ::: "memory");
    loadA(0, 0, af0);
    loadB(0, 0, b0);
    // cross-wave drain of prologue reads before any later restage of buf0/kk0
    __asm__ volatile("s_waitcnt lgkmcnt(0)" ::: "memory");
    __asm__ volatile("s_barrier" ::: "memory");

    for (int T = 0; T < nk; T++) {
        int buf = T & 1, nbuf = buf ^ 1;
        bool s0 = (T + 1 < nk);            // stage kk1(T+1) at p0
        bool s1 = (T + 2 < nk);            // stage kk0(T+2) at p1

        // ---- p0: MFMA(kk0: af0,b0); read kk1(T)->af1,b1; stage kk1(T+1)->nbuf ----
        PH_TOP();
        loadA(buf, 1, af1);
        loadB(buf, 1, b1);
        if (s0) { stageA(nbuf, 1, T + 1); stageB(nbuf, 1, T + 1); }
        __builtin_amdgcn_sched_barrier(0);
        __builtin_amdgcn_s_setprio(1);
        MFMA16(af0, b0);
        __builtin_amdgcn_s_setprio(0);
        PH_BOT(s0);

        // ---- p1: MFMA(kk1: af1,b1); read kk0(T+1)->af0,b0; stage kk0(T+2)->buf ----
        PH_TOP();
        if (s0) { loadA(nbuf, 0, af0); loadB(nbuf, 0, b0); }
        if (s1) { stageA(buf, 0, T + 2); stageB(buf, 0, T + 2); }
        __builtin_amdgcn_sched_barrier(0);
        __builtin_amdgcn_s_setprio(1);
        MFMA16(af1, b1);
        __builtin_amdgcn_s_setprio(0);
        PH_BOT(s1);
    }

    // ---- epilogue: per-wave 64-col group = one head (Q/K rmsnorm) or V chunk ----
    int nglob = n0 + wn * 64;
    if (nglob < 2048) {
        int isK = nglob >> 10;
        int h = (nglob >> 6) & 15;
        const float* wv = isK ? wk : wq;
        half_t* dst = isK ? Kh : Qh;
        float post = isK ? 1.0f : LOG2E;   // pre-scale Q so attn works in log2 domain
        #pragma unroll
        for (int mi = 0; mi < 4; mi++) {
            #pragma unroll
            for (int r = 0; r < 4; r++) {
                int gr = m0 + wm * 64 + mi * 16 + quad * 4 + r;
                float v[4]; float ss = 0.f;
                #pragma unroll
                for (int ni = 0; ni < 4; ni++) {
                    v[ni] = acc[mi][ni][r] + bias[nglob + ni * 16 + lrow];
                    ss += v[ni] * v[ni];
                }
                ss += __shfl_xor(ss, 1);
                ss += __shfl_xor(ss, 2);
                ss += __shfl_xor(ss, 4);
                ss += __shfl_xor(ss, 8);
                float rr = rsqrtf(ss * (1.0f / 64.0f) + 1e-6f) * post;
                int bb = gr >> 11, s = gr & 2047;
                size_t rowbase = ((size_t)((bb * 16 + h) * 2048 + s)) * 64;
                #pragma unroll
                for (int ni = 0; ni < 4; ni++) {
                    int d = ni * 16 + lrow;
                    dst[rowbase + d] = (half_t)(v[ni] * rr * wv[d]);
                }
            }
        }
    } else {
        // V part: store transposed into Vt[bh][d][s]
        #pragma unroll
        for (int mi = 0; mi < 4; mi++) {
            int gr = m0 + wm * 64 + mi * 16 + quad * 4;   // s-base, 4-aligned
            int bb = gr >> 11, s = gr & 2047;
            #pragma unroll
            for (int ni = 0; ni < 4; ni++) {
                int dg = nglob + ni * 16 + lrow - 2048;   // 0..1023
                float bv = bias[nglob + ni * 16 + lrow];
                half4v oh;
                #pragma unroll
                for (int r = 0; r < 4; r++) oh[r] = (half_t)(acc[mi][ni][r] + bv);
                *(half4v*)(Vt + ((size_t)((bb * 16 + (dg >> 6)) * 64 + (dg & 63))) * 2048 + s) = oh;
            }
        }
    }
#undef PH_TOP
#undef PH_BOT
#undef MFMA16
}

// ---------------- GEMM: C[M][N] = A[M][K] * Bt[N][K]^T + bias (output proj) ----------
// (r10 config: triple-buffered GLDS, raw barriers, bank-swizzle, 3 waves/SIMD)
template <int MODE>
__global__ __launch_bounds__(256, 3) void gemm_f16(
    const half_t* __restrict__ A,   // [M][K]
    const half_t* __restrict__ Bt,  // [N][K]
    const float* __restrict__ bias, // [N]
    void* __restrict__ Cout,
    int M, int N, int K,
    const float* __restrict__ wq, const float* __restrict__ wk,
    half_t* __restrict__ Qh, half_t* __restrict__ Kh)
{
    __shared__ __align__(16) half_t As[3][128 * 32];
    __shared__ __align__(16) half_t Bs[3][128 * 32];
    int t = threadIdx.x;
    int lane = t & 63, w = t >> 6;
    int m0 = blockIdx.x * 128, n0 = blockIdx.y * 128;
    int wm = (w >> 1) * 64, wn = (w & 1) * 64;
    int lrow = lane & 15, quad = lane >> 4;

    int lc = ((t & 3) - (t >> 3)) & 3;
    const half_t* gA = A  + (size_t)(m0 + (t >> 2)) * K + lc * 8;
    const half_t* gB = Bt + (size_t)(n0 + (t >> 2)) * K + lc * 8;
    half_t* ldsA[3] = { &As[0][w * 512], &As[1][w * 512], &As[2][w * 512] };
    half_t* ldsB[3] = { &Bs[0][w * 512], &Bs[1][w * 512], &Bs[2][w * 512] };

    int posq = (quad + (lrow >> 1)) & 3;

    float4v acc[4][4] = {};

    GLDS16(gA,                       ldsA[0]);
    GLDS16(gA + (size_t)64 * K,      ldsA[0] + 2048);
    GLDS16(gB,                       ldsB[0]);
    GLDS16(gB + (size_t)64 * K,      ldsB[0] + 2048);
    GLDS16(gA + 32,                  ldsA[1]);
    GLDS16(gA + (size_t)64 * K + 32, ldsA[1] + 2048);
    GLDS16(gB + 32,                  ldsB[1]);
    GLDS16(gB + (size_t)64 * K + 32, ldsB[1] + 2048);

    int nk = K >> 5;
    for (int ki = 0; ki < nk; ki++) {
        int cur = ki % 3, pre = (ki + 2) % 3;
        BAR_LGKM();
        if (ki + 2 < nk) {
            int kp = (ki + 2) << 5;
            GLDS16(gA + kp,                  ldsA[pre]);
            GLDS16(gA + (size_t)64 * K + kp, ldsA[pre] + 2048);
            GLDS16(gB + kp,                  ldsB[pre]);
            GLDS16(gB + (size_t)64 * K + kp, ldsB[pre] + 2048);
            BAR_VM(8);
        } else if (ki + 1 < nk) {
            BAR_VM(4);
        } else {
            BAR_VM(0);
        }
        half8 af[4], bf[4];
        for (int i = 0; i < 4; i++) af[i] = *(const half8*)(&As[cur][(wm + i * 16 + lrow) * 32 + posq * 8]);
        for (int i = 0; i < 4; i++) bf[i] = *(const half8*)(&Bs[cur][(wn + i * 16 + lrow) * 32 + posq * 8]);
        for (int mi = 0; mi < 4; mi++)
            for (int ni = 0; ni < 4; ni++)
                acc[mi][ni] = __builtin_amdgcn_mfma_f32_16x16x32_f16(af[mi], bf[ni], acc[mi][ni], 0, 0, 0);
    }

    if (MODE == 0) {
        float* out = (float*)Cout;
        for (int mi = 0; mi < 4; mi++)
            for (int ni = 0; ni < 4; ni++)
                for (int r = 0; r < 4; r++) {
                    int gr = m0 + wm + mi * 16 + quad * 4 + r;
                    int gc = n0 + wn + ni * 16 + lrow;
                    out[(size_t)gr * N + gc] = acc[mi][ni][r] + bias[gc];
                }
    } else {
        int nglob = n0 + wn;            // 64-aligned; one head per wave
        if (nglob < 2048) {
            int isK = nglob >> 10;
            int h = (nglob >> 6) & 15;
            const float* wv = isK ? wk : wq;
            half_t* dst = isK ? Kh : Qh;
            float post = isK ? 1.0f : LOG2E;
            for (int mi = 0; mi < 4; mi++)
                for (int r = 0; r < 4; r++) {
                    int gr = m0 + wm + mi * 16 + quad * 4 + r;
                    float v[4]; float ss = 0.f;
                    for (int ni = 0; ni < 4; ni++) {
                        v[ni] = acc[mi][ni][r] + bias[nglob + ni * 16 + lrow];
                        ss += v[ni] * v[ni];
                    }
                    ss += __shfl_xor(ss, 1);
                    ss += __shfl_xor(ss, 2);
                    ss += __shfl_xor(ss, 4);
                    ss += __shfl_xor(ss, 8);
                    float rr = rsqrtf(ss * (1.0f / 64.0f) + 1e-6f) * post;
                    int bb = gr >> 11, s = gr & 2047;
                    size_t rowbase = ((size_t)((bb * 16 + h) * 2048 + s)) * 64;
                    for (int ni = 0; ni < 4; ni++) {
                        int d = ni * 16 + lrow;
                        dst[rowbase + d] = (half_t)(v[ni] * rr * wv[d]);
                    }
                }
        } else {
            half_t* Vt = (half_t*)Cout;
            for (int mi = 0; mi < 4; mi++) {
                int gr = m0 + wm + mi * 16 + quad * 4;
                int bb = gr >> 11, s = gr & 2047;
                for (int ni = 0; ni < 4; ni++) {
                    int dg = nglob + ni * 16 + lrow - 2048;
                    float bv = bias[nglob + ni * 16 + lrow];
                    half4v oh;
                    for (int r = 0; r < 4; r++) oh[r] = (half_t)(acc[mi][ni][r] + bv);
                    *(half4v*)(Vt + ((size_t)((bb * 16 + (dg >> 6)) * 64 + (dg & 63))) * 2048 + s) = oh;
                }
            }
        }
    }
}

// ---------------- Flash attention, causal, no scale (Q pre-scaled by LOG2E) --
// 8 waves / 128 q-rows, paired q-tiles (i,15-i), grid (bh, pair) for XCD L2.
__global__ __launch_bounds__(512, 4) void attn(
    const half_t* __restrict__ Qh, const half_t* __restrict__ Kh, const half_t* __restrict__ Vt,
    half_t* __restrict__ Z)
{
    __shared__ __align__(16) half_t Ks[2][128 * 64];  // [buf][key][d], pos = chunk ^ (key&7)
    __shared__ __align__(16) half_t Vs[2][64 * 128];  // [buf][d][key], pos = chunk ^ (d&7)
    __shared__ __align__(16) half_t Ps[8][16 * 64];   // per-wave [q][key-half]

    int bh = blockIdx.x;
    int b = bh >> 4, h = bh & 15;
    int t = threadIdx.x, lane = t & 63, w = t >> 6;
    int lrow = lane & 15, quad = lane >> 4;

    int scc = (lane & 7) ^ ((lane >> 3) & 7);
    const half_t* gK0 = Kh + ((size_t)bh * 2048 + w * 16 + (lane >> 3)) * 64 + scc * 8;
    int vr0 = w * 8 + (lane >> 4);
    int vc0 = (lane & 15) ^ (lane >> 4);
    int vc1 = (lane & 15) ^ ((lane >> 4) + 4);
    const half_t* gV0 = Vt + ((size_t)bh * 64 + vr0) * 2048 + vc0 * 8;
    const half_t* gV1 = Vt + ((size_t)bh * 64 + vr0 + 4) * 2048 + vc1 * 8;
    half_t* ldsK[2] = { &Ks[0][w * 1024], &Ks[1][w * 1024] };
    half_t* ldsV[2] = { &Vs[0][w * 1024], &Vs[1][w * 1024] };

    int sw = lrow & 7;
    int cA = (quad ^ sw) * 8;
    int cB = ((quad + 4) ^ sw) * 8;
    half_t* PsW = &Ps[w][lrow * 64];

    for (int pass = 0; pass < 2; pass++) {
        int qt = pass ? (15 - (int)blockIdx.y) : (int)blockIdx.y;
        int q0w = qt * 128 + w * 16;

        const half_t* Qbase = Qh + ((size_t)bh * 2048 + q0w + lrow) * 64;
        half8 qf0 = *(const half8*)(Qbase + quad * 8);
        half8 qf1 = *(const half8*)(Qbase + 32 + quad * 8);

        float4v ot[4] = {};
        float m = -__builtin_inff(), l = 0.f;

        int nt = qt + 1;
        __syncthreads();
        GLDS16(gK0,       ldsK[0]);
        GLDS16(gK0 + 512, ldsK[0] + 512);
        GLDS16(gV0,       ldsV[0]);
        GLDS16(gV1,       ldsV[0] + 512);

        for (int kt = 0; kt < nt; kt++) {
            int cur = kt & 1, nxt = cur ^ 1;
            int kb = kt * 128;
            BAR_LGKM();
            if (kt + 1 < nt) {
                size_t ko = (size_t)(kb + 128);
                GLDS16(gK0 + ko * 64,       ldsK[nxt]);
                GLDS16(gK0 + ko * 64 + 512, ldsK[nxt] + 512);
                GLDS16(gV0 + ko,            ldsV[nxt]);
                GLDS16(gV1 + ko,            ldsV[nxt] + 512);
                BAR_VM(4);
            } else {
                BAR_VM(0);
            }

            float4v st[8];
            for (int f = 0; f < 8; f++) {
                float4v z = {};
                const half_t* kr = &Ks[cur][(f * 16 + lrow) * 64];
                half8 k0 = *(const half8*)(kr + cA);
                half8 k1 = *(const half8*)(kr + cB);
                z = __builtin_amdgcn_mfma_f32_16x16x32_f16(k0, qf0, z, 0, 0, 0);
                z = __builtin_amdgcn_mfma_f32_16x16x32_f16(k1, qf1, z, 0, 0, 0);
                st[f] = z;
            }
            if (kb + 127 > q0w) {
                int qabs = q0w + lrow;
                for (int f = 0; f < 8; f++)
                    for (int r = 0; r < 4; r++) {
                        int key = kb + f * 16 + quad * 4 + r;
                        if (key > qabs) st[f][r] = -__builtin_inff();
                    }
            }
            float tm = st[0][0];
            for (int f = 0; f < 8; f++)
                for (int r = 0; r < 4; r++) tm = fmaxf(tm, st[f][r]);
            tm = fmaxf(tm, __shfl_xor(tm, 16));
            tm = fmaxf(tm, __shfl_xor(tm, 32));
            float mn = fmaxf(m, tm);
            float alpha = __builtin_amdgcn_exp2f(m - mn);
            m = mn;
            float rs = 0.f;
            uint2 pw1[4];
            for (int f = 0; f < 8; f++) {
                float p0 = __builtin_amdgcn_exp2f(st[f][0] - mn);
                float p1 = __builtin_amdgcn_exp2f(st[f][1] - mn);
                float p2 = __builtin_amdgcn_exp2f(st[f][2] - mn);
                float p3 = __builtin_amdgcn_exp2f(st[f][3] - mn);
                rs += (p0 + p1) + (p2 + p3);
                uint2 pw;
                pw.x = __builtin_bit_cast(unsigned, __builtin_amdgcn_cvt_pkrtz(p0, p1));
                pw.y = __builtin_bit_cast(unsigned, __builtin_amdgcn_cvt_pkrtz(p2, p3));
                if (f < 4) {
                    int cc = (2 * f + (quad >> 1)) ^ sw;
                    *(uint2*)(PsW + cc * 8 + (quad & 1) * 4) = pw;
                } else {
                    pw1[f - 4] = pw;
                }
            }
            rs += __shfl_xor(rs, 16);
            rs += __shfl_xor(rs, 32);
            l = l * alpha + rs;
            for (int f2 = 0; f2 < 4; f2++)
                for (int r = 0; r < 4; r++) ot[f2][r] *= alpha;

            __asm__ volatile("s_waitcnt lgkmcnt(0)" ::: "memory");
            half8 p0v = *(const half8*)(PsW + cA);
            half8 p1v = *(const half8*)(PsW + cB);
            for (int f2 = 0; f2 < 4; f2++) {
                int row = f2 * 16 + lrow;
                half8 v0 = *(const half8*)(&Vs[cur][row * 128 + ((quad ^ sw)) * 8]);
                half8 v1 = *(const half8*)(&Vs[cur][row * 128 + (((4 + quad) ^ sw)) * 8]);
                ot[f2] = __builtin_amdgcn_mfma_f32_16x16x32_f16(v0, p0v, ot[f2], 0, 0, 0);
                ot[f2] = __builtin_amdgcn_mfma_f32_16x16x32_f16(v1, p1v, ot[f2], 0, 0, 0);
            }
            for (int f = 0; f < 4; f++) {
                int cc = (2 * f + (quad >> 1)) ^ sw;
                *(uint2*)(PsW + cc * 8 + (quad & 1) * 4) = pw1[f];
            }
            __asm__ volatile("s_waitcnt lgkmcnt(0)" ::: "memory");
            half8 p2v = *(const half8*)(PsW + cA);
            half8 p3v = *(const half8*)(PsW + cB);
            for (int f2 = 0; f2 < 4; f2++) {
                int row = f2 * 16 + lrow;
                half8 v2 = *(const half8*)(&Vs[cur][row * 128 + (((8 + quad) ^ sw)) * 8]);
                half8 v3 = *(const half8*)(&Vs[cur][row * 128 + (((12 + quad) ^ sw)) * 8]);
                ot[f2] = __builtin_amdgcn_mfma_f32_16x16x32_f16(v2, p2v, ot[f2], 0, 0, 0);
                ot[f2] = __builtin_amdgcn_mfma_f32_16x16x32_f16(v3, p3v, ot[f2], 0, 0, 0);
            }
        }

        float inv = 1.0f / l;
        size_t base = ((size_t)(b * 2048) + q0w + lrow) * 1024 + h * 64;
        for (int f2 = 0; f2 < 4; f2++) {
            half4v oh;
            for (int r = 0; r < 4; r++) oh[r] = (half_t)(ot[f2][r] * inv);
            *(half4v*)(Z + base + f2 * 16 + quad * 4) = oh;
        }
    }
}

// ---------------- launch ----------------
extern "C" void kernel_launch(void* const* d_in, const int* in_sizes, int n_in,
                              void* d_out, int out_size, void* d_ws, size_t ws_size,
                              hipStream_t stream)
{
    const float* x     = (const float*)d_in[0];
    // d_in[1] = mask (causal, known analytically) - unused
    const float* W_qkv = (const float*)d_in[2];
    const float* b_qkv = (const float*)d_in[3];
    const float* W_o   = (const float*)d_in[4];
    const float* b_o   = (const float*)d_in[5];
    const float* wq    = (const float*)d_in[6];
    const float* wk    = (const float*)d_in[7];
    float* out = (float*)d_out;

    char* ws = (char*)d_ws;
    half_t* xh   = (half_t*)(ws);                     // 16 MB (reused as zh after attn)
    half_t* Wqt  = (half_t*)(ws + (16ull << 20));     // 6 MB
    half_t* Wot  = (half_t*)(ws + (22ull << 20));     // 2 MB
    half_t* Qh   = (half_t*)(ws + (40ull << 20));     // 16 MB
    half_t* Kh   = (half_t*)(ws + (56ull << 20));     // 16 MB
    half_t* Vt   = (half_t*)(ws + (72ull << 20));     // 16 MB
    half_t* zh   = xh;

    cast_f32_f16<<<8192, 256, 0, stream>>>(x, xh, 8192 * 1024);
    transpose_cast<<<dim3(96, 32), dim3(32, 8), 0, stream>>>(W_qkv, Wqt, 1024, 3072);
    transpose_cast<<<dim3(32, 32), dim3(32, 8), 0, stream>>>(W_o, Wot, 1024, 1024);
    gemm_qkv<<<768, 512, 0, stream>>>(xh, Wqt, b_qkv, wq, wk, Qh, Kh, Vt, 8192, 3072, 1024);
    attn<<<dim3(64, 8), 512, 0, stream>>>(Qh, Kh, Vt, zh);
    gemm_f16<0><<<dim3(64, 8), 256, 0, stream>>>(zh, Wot, b_o, out, 8192, 1024, 1024,
                                                 nullptr, nullptr, nullptr, nullptr);
}

// Round 7
// 272.444 us; speedup vs baseline: 1.0058x; 1.0058x over previous
//
#include <hip/hip_runtime.h>
#include <cmath>

typedef _Float16 half_t;
typedef _Float16 half8 __attribute__((ext_vector_type(8)));
typedef _Float16 half4v __attribute__((ext_vector_type(4)));
typedef float float4v __attribute__((ext_vector_type(4)));

#define LOG2E 1.44269504088896340736f

#define GLDS16(g, l)                                                                   \
    __builtin_amdgcn_global_load_lds((const __attribute__((address_space(1))) void*)(g), \
                                     (__attribute__((address_space(3))) void*)(l), 16, 0, 0)

// raw barriers: no compiler-inserted vmcnt(0) drain (the __syncthreads trap)
#define BAR_LGKM() __asm__ volatile("s_waitcnt lgkmcnt(0)\n\ts_barrier" ::: "memory")
#define BAR_VM(n)  __asm__ volatile("s_waitcnt vmcnt(" #n ")\n\ts_barrier" ::: "memory")

// ---------------- cast fp32 -> fp16 ----------------
__global__ void cast_f32_f16(const float* __restrict__ in, half_t* __restrict__ out, int n) {
    int i = (blockIdx.x * blockDim.x + threadIdx.x) * 4;
    if (i >= n) return;
    float4 v = *(const float4*)(in + i);
    half4v o;
    o[0] = (half_t)v.x; o[1] = (half_t)v.y; o[2] = (half_t)v.z; o[3] = (half_t)v.w;
    *(half4v*)(out + i) = o;
}

// ---------------- transpose + cast: in fp32 [R][C] -> out fp16 [C][R] ----------------
__global__ void transpose_cast(const float* __restrict__ in, half_t* __restrict__ out, int R, int C) {
    __shared__ float tile[32][33];
    int c0 = blockIdx.x * 32, r0 = blockIdx.y * 32;
    int tx = threadIdx.x, ty = threadIdx.y; // block (32,8)
    for (int p = 0; p < 4; p++) {
        int r = r0 + ty + p * 8;
        tile[ty + p * 8][tx] = in[(size_t)r * C + c0 + tx];
    }
    __syncthreads();
    for (int p = 0; p < 4; p++) {
        int c = c0 + ty + p * 8;
        out[(size_t)c * R + r0 + tx] = (half_t)tile[tx][ty + p * 8];
    }
}

// ---------------- GEMM: C[M][N] = A[M][K] * Bt[N][K]^T + bias ----------------
// r7 config: the r0 proven structure (128x128 tile, BK=32, multi-block/CU overlap
// regime — the only regime measured >600 TF here; all 1-block/CU phase schedules
// landed at 22-25% MfmaUtil in r1-r6) with occupancy pushed 3 -> 4 blocks/CU:
//   - DOUBLE buffer (LDS 48KB -> 32KB; LDS cap becomes 5 blocks/CU)
//   - __launch_bounds__(256,4): reg cap 128/wave -> 4 waves/SIMD = 4 blocks/CU
// Ledger (per-wave, 4 GLDS per stage group S_k):
//   prologue: issue S0,S1 (8 out); vmcnt(4)+bar -> S0 landed.
//   iter ki:  read buf[ki&1] (committed), MFMA;
//             BAR_LGKM (all waves' reads done -> restage safe);
//             stage S_{ki+2} into buf[ki&1] (8 out); BAR_VM(4) -> S_{ki+1} landed.
//   tail:     ki=nk-2: no stage, BAR_VM(0); ki=nk-1: no barriers (epilogue has no LDS).
template <int MODE>
__global__ __launch_bounds__(256, 4) void gemm_f16(
    const half_t* __restrict__ A,   // [M][K]
    const half_t* __restrict__ Bt,  // [N][K]
    const float* __restrict__ bias, // [N]
    void* __restrict__ Cout,
    int M, int N, int K,
    const float* __restrict__ wq, const float* __restrict__ wk,
    half_t* __restrict__ Qh, half_t* __restrict__ Kh)
{
    __shared__ __align__(16) half_t As[2][128 * 32];
    __shared__ __align__(16) half_t Bs[2][128 * 32];
    int t = threadIdx.x;
    int lane = t & 63, w = t >> 6;
    int m0 = blockIdx.x * 128, n0 = blockIdx.y * 128;
    int wm = (w >> 1) * 64, wn = (w & 1) * 64;
    int lrow = lane & 15, quad = lane >> 4;

    int lc = ((t & 3) - (t >> 3)) & 3;
    const half_t* gA = A  + (size_t)(m0 + (t >> 2)) * K + lc * 8;
    const half_t* gB = Bt + (size_t)(n0 + (t >> 2)) * K + lc * 8;
    half_t* ldsA[2] = { &As[0][w * 512], &As[1][w * 512] };
    half_t* ldsB[2] = { &Bs[0][w * 512], &Bs[1][w * 512] };

    int posq = (quad + (lrow >> 1)) & 3;

    float4v acc[4][4] = {};

    // prologue: stage tile0 -> buf0, tile1 -> buf1 (8 GLDS/wave)
    GLDS16(gA,                       ldsA[0]);
    GLDS16(gA + (size_t)64 * K,      ldsA[0] + 2048);
    GLDS16(gB,                       ldsB[0]);
    GLDS16(gB + (size_t)64 * K,      ldsB[0] + 2048);
    GLDS16(gA + 32,                  ldsA[1]);
    GLDS16(gA + (size_t)64 * K + 32, ldsA[1] + 2048);
    GLDS16(gB + 32,                  ldsB[1]);
    GLDS16(gB + (size_t)64 * K + 32, ldsB[1] + 2048);
    __asm__ volatile("s_waitcnt vmcnt(4)" ::: "memory");   // tile0 landed
    __asm__ volatile("s_barrier" ::: "memory");

    int nk = K >> 5;
    for (int ki = 0; ki < nk; ki++) {
        int cur = ki & 1;
        half8 af[4], bf[4];
        for (int i = 0; i < 4; i++) af[i] = *(const half8*)(&As[cur][(wm + i * 16 + lrow) * 32 + posq * 8]);
        for (int i = 0; i < 4; i++) bf[i] = *(const half8*)(&Bs[cur][(wn + i * 16 + lrow) * 32 + posq * 8]);
        for (int mi = 0; mi < 4; mi++)
            for (int ni = 0; ni < 4; ni++)
                acc[mi][ni] = __builtin_amdgcn_mfma_f32_16x16x32_f16(af[mi], bf[ni], acc[mi][ni], 0, 0, 0);

        if (ki + 1 < nk) {
            BAR_LGKM();                          // all waves done reading buf[cur]
            if (ki + 2 < nk) {
                int kp = (ki + 2) << 5;
                GLDS16(gA + kp,                  ldsA[cur]);
                GLDS16(gA + (size_t)64 * K + kp, ldsA[cur] + 2048);
                GLDS16(gB + kp,                  ldsB[cur]);
                GLDS16(gB + (size_t)64 * K + kp, ldsB[cur] + 2048);
                BAR_VM(4);                       // tile ki+1 landed
            } else {
                BAR_VM(0);                       // final tile landed
            }
        }
    }

    if (MODE == 0) {
        float* out = (float*)Cout;
        for (int mi = 0; mi < 4; mi++)
            for (int ni = 0; ni < 4; ni++)
                for (int r = 0; r < 4; r++) {
                    int gr = m0 + wm + mi * 16 + quad * 4 + r;
                    int gc = n0 + wn + ni * 16 + lrow;
                    out[(size_t)gr * N + gc] = acc[mi][ni][r] + bias[gc];
                }
    } else {
        int nglob = n0 + wn;            // 64-aligned; one head per wave
        if (nglob < 2048) {
            int isK = nglob >> 10;
            int h = (nglob >> 6) & 15;
            const float* wv = isK ? wk : wq;
            half_t* dst = isK ? Kh : Qh;
            float post = isK ? 1.0f : LOG2E;   // pre-scale Q so attn works in log2 domain
            for (int mi = 0; mi < 4; mi++)
                for (int r = 0; r < 4; r++) {
                    int gr = m0 + wm + mi * 16 + quad * 4 + r;
                    float v[4]; float ss = 0.f;
                    for (int ni = 0; ni < 4; ni++) {
                        v[ni] = acc[mi][ni][r] + bias[nglob + ni * 16 + lrow];
                        ss += v[ni] * v[ni];
                    }
                    ss += __shfl_xor(ss, 1);
                    ss += __shfl_xor(ss, 2);
                    ss += __shfl_xor(ss, 4);
                    ss += __shfl_xor(ss, 8);
                    float rr = rsqrtf(ss * (1.0f / 64.0f) + 1e-6f) * post;
                    int bb = gr >> 11, s = gr & 2047;
                    size_t rowbase = ((size_t)((bb * 16 + h) * 2048 + s)) * 64;
                    for (int ni = 0; ni < 4; ni++) {
                        int d = ni * 16 + lrow;
                        dst[rowbase + d] = (half_t)(v[ni] * rr * wv[d]);
                    }
                }
        } else {
            // V part: store transposed into Vt[bh][d][s]
            half_t* Vt = (half_t*)Cout;
            for (int mi = 0; mi < 4; mi++) {
                int gr = m0 + wm + mi * 16 + quad * 4;   // s-base, 4-aligned
                int bb = gr >> 11, s = gr & 2047;
                for (int ni = 0; ni < 4; ni++) {
                    int dg = nglob + ni * 16 + lrow - 2048;   // 0..1023
                    float bv = bias[nglob + ni * 16 + lrow];
                    half4v oh;
                    for (int r = 0; r < 4; r++) oh[r] = (half_t)(acc[mi][ni][r] + bv);
                    *(half4v*)(Vt + ((size_t)((bb * 16 + (dg >> 6)) * 64 + (dg & 63))) * 2048 + s) = oh;
                }
            }
        }
    }
}

// ---------------- Flash attention, causal, no scale (Q pre-scaled by LOG2E) --
// 8 waves / 128 q-rows, paired q-tiles (i,15-i), grid (bh, pair) for XCD L2.
__global__ __launch_bounds__(512, 4) void attn(
    const half_t* __restrict__ Qh, const half_t* __restrict__ Kh, const half_t* __restrict__ Vt,
    half_t* __restrict__ Z)
{
    __shared__ __align__(16) half_t Ks[2][128 * 64];  // [buf][key][d], pos = chunk ^ (key&7)
    __shared__ __align__(16) half_t Vs[2][64 * 128];  // [buf][d][key], pos = chunk ^ (d&7)
    __shared__ __align__(16) half_t Ps[8][16 * 64];   // per-wave [q][key-half]

    int bh = blockIdx.x;
    int b = bh >> 4, h = bh & 15;
    int t = threadIdx.x, lane = t & 63, w = t >> 6;
    int lrow = lane & 15, quad = lane >> 4;

    int scc = (lane & 7) ^ ((lane >> 3) & 7);
    const half_t* gK0 = Kh + ((size_t)bh * 2048 + w * 16 + (lane >> 3)) * 64 + scc * 8;
    int vr0 = w * 8 + (lane >> 4);
    int vc0 = (lane & 15) ^ (lane >> 4);
    int vc1 = (lane & 15) ^ ((lane >> 4) + 4);
    const half_t* gV0 = Vt + ((size_t)bh * 64 + vr0) * 2048 + vc0 * 8;
    const half_t* gV1 = Vt + ((size_t)bh * 64 + vr0 + 4) * 2048 + vc1 * 8;
    half_t* ldsK[2] = { &Ks[0][w * 1024], &Ks[1][w * 1024] };
    half_t* ldsV[2] = { &Vs[0][w * 1024], &Vs[1][w * 1024] };

    int sw = lrow & 7;
    int cA = (quad ^ sw) * 8;
    int cB = ((quad + 4) ^ sw) * 8;
    half_t* PsW = &Ps[w][lrow * 64];

    for (int pass = 0; pass < 2; pass++) {
        int qt = pass ? (15 - (int)blockIdx.y) : (int)blockIdx.y;
        int q0w = qt * 128 + w * 16;

        const half_t* Qbase = Qh + ((size_t)bh * 2048 + q0w + lrow) * 64;
        half8 qf0 = *(const half8*)(Qbase + quad * 8);
        half8 qf1 = *(const half8*)(Qbase + 32 + quad * 8);

        float4v ot[4] = {};
        float m = -__builtin_inff(), l = 0.f;

        int nt = qt + 1;
        __syncthreads();
        GLDS16(gK0,       ldsK[0]);
        GLDS16(gK0 + 512, ldsK[0] + 512);
        GLDS16(gV0,       ldsV[0]);
        GLDS16(gV1,       ldsV[0] + 512);

        for (int kt = 0; kt < nt; kt++) {
            int cur = kt & 1, nxt = cur ^ 1;
            int kb = kt * 128;
            BAR_LGKM();
            if (kt + 1 < nt) {
                size_t ko = (size_t)(kb + 128);
                GLDS16(gK0 + ko * 64,       ldsK[nxt]);
                GLDS16(gK0 + ko * 64 + 512, ldsK[nxt] + 512);
                GLDS16(gV0 + ko,            ldsV[nxt]);
                GLDS16(gV1 + ko,            ldsV[nxt] + 512);
                BAR_VM(4);
            } else {
                BAR_VM(0);
            }

            float4v st[8];
            for (int f = 0; f < 8; f++) {
                float4v z = {};
                const half_t* kr = &Ks[cur][(f * 16 + lrow) * 64];
                half8 k0 = *(const half8*)(kr + cA);
                half8 k1 = *(const half8*)(kr + cB);
                z = __builtin_amdgcn_mfma_f32_16x16x32_f16(k0, qf0, z, 0, 0, 0);
                z = __builtin_amdgcn_mfma_f32_16x16x32_f16(k1, qf1, z, 0, 0, 0);
                st[f] = z;
            }
            if (kb + 127 > q0w) {
                int qabs = q0w + lrow;
                for (int f = 0; f < 8; f++)
                    for (int r = 0; r < 4; r++) {
                        int key = kb + f * 16 + quad * 4 + r;
                        if (key > qabs) st[f][r] = -__builtin_inff();
                    }
            }
            float tm = st[0][0];
            for (int f = 0; f < 8; f++)
                for (int r = 0; r < 4; r++) tm = fmaxf(tm, st[f][r]);
            tm = fmaxf(tm, __shfl_xor(tm, 16));
            tm = fmaxf(tm, __shfl_xor(tm, 32));
            float mn = fmaxf(m, tm);
            float alpha = __builtin_amdgcn_exp2f(m - mn);
            m = mn;
            float rs = 0.f;
            uint2 pw1[4];
            for (int f = 0; f < 8; f++) {
                float p0 = __builtin_amdgcn_exp2f(st[f][0] - mn);
                float p1 = __builtin_amdgcn_exp2f(st[f][1] - mn);
                float p2 = __builtin_amdgcn_exp2f(st[f][2] - mn);
                float p3 = __builtin_amdgcn_exp2f(st[f][3] - mn);
                rs += (p0 + p1) + (p2 + p3);
                uint2 pw;
                pw.x = __builtin_bit_cast(unsigned, __builtin_amdgcn_cvt_pkrtz(p0, p1));
                pw.y = __builtin_bit_cast(unsigned, __builtin_amdgcn_cvt_pkrtz(p2, p3));
                if (f < 4) {
                    int cc = (2 * f + (quad >> 1)) ^ sw;
                    *(uint2*)(PsW + cc * 8 + (quad & 1) * 4) = pw;
                } else {
                    pw1[f - 4] = pw;
                }
            }
            rs += __shfl_xor(rs, 16);
            rs += __shfl_xor(rs, 32);
            l = l * alpha + rs;
            for (int f2 = 0; f2 < 4; f2++)
                for (int r = 0; r < 4; r++) ot[f2][r] *= alpha;

            __asm__ volatile("s_waitcnt lgkmcnt(0)" ::: "memory");
            half8 p0v = *(const half8*)(PsW + cA);
            half8 p1v = *(const half8*)(PsW + cB);
            for (int f2 = 0; f2 < 4; f2++) {
                int row = f2 * 16 + lrow;
                half8 v0 = *(const half8*)(&Vs[cur][row * 128 + ((quad ^ sw)) * 8]);
                half8 v1 = *(const half8*)(&Vs[cur][row * 128 + (((4 + quad) ^ sw)) * 8]);
                ot[f2] = __builtin_amdgcn_mfma_f32_16x16x32_f16(v0, p0v, ot[f2], 0, 0, 0);
                ot[f2] = __builtin_amdgcn_mfma_f32_16x16x32_f16(v1, p1v, ot[f2], 0, 0, 0);
            }
            for (int f = 0; f < 4; f++) {
                int cc = (2 * f + (quad >> 1)) ^ sw;
                *(uint2*)(PsW + cc * 8 + (quad & 1) * 4) = pw1[f];
            }
            __asm__ volatile("s_waitcnt lgkmcnt(0)" ::: "memory");
            half8 p2v = *(const half8*)(PsW + cA);
            half8 p3v = *(const half8*)(PsW + cB);
            for (int f2 = 0; f2 < 4; f2++) {
                int row = f2 * 16 + lrow;
                half8 v2 = *(const half8*)(&Vs[cur][row * 128 + (((8 + quad) ^ sw)) * 8]);
                half8 v3 = *(const half8*)(&Vs[cur][row * 128 + (((12 + quad) ^ sw)) * 8]);
                ot[f2] = __builtin_amdgcn_mfma_f32_16x16x32_f16(v2, p2v, ot[f2], 0, 0, 0);
                ot[f2] = __builtin_amdgcn_mfma_f32_16x16x32_f16(v3, p3v, ot[f2], 0, 0, 0);
            }
        }

        float inv = 1.0f / l;
        size_t base = ((size_t)(b * 2048) + q0w + lrow) * 1024 + h * 64;
        for (int f2 = 0; f2 < 4; f2++) {
            half4v oh;
            for (int r = 0; r < 4; r++) oh[r] = (half_t)(ot[f2][r] * inv);
            *(half4v*)(Z + base + f2 * 16 + quad * 4) = oh;
        }
    }
}

// ---------------- launch ----------------
extern "C" void kernel_launch(void* const* d_in, const int* in_sizes, int n_in,
                              void* d_out, int out_size, void* d_ws, size_t ws_size,
                              hipStream_t stream)
{
    const float* x     = (const float*)d_in[0];
    // d_in[1] = mask (causal, known analytically) - unused
    const float* W_qkv = (const float*)d_in[2];
    const float* b_qkv = (const float*)d_in[3];
    const float* W_o   = (const float*)d_in[4];
    const float* b_o   = (const float*)d_in[5];
    const float* wq    = (const float*)d_in[6];
    const float* wk    = (const float*)d_in[7];
    float* out = (float*)d_out;

    char* ws = (char*)d_ws;
    half_t* xh   = (half_t*)(ws);                     // 16 MB (reused as zh after attn)
    half_t* Wqt  = (half_t*)(ws + (16ull << 20));     // 6 MB
    half_t* Wot  = (half_t*)(ws + (22ull << 20));     // 2 MB
    half_t* Qh   = (half_t*)(ws + (40ull << 20));     // 16 MB
    half_t* Kh   = (half_t*)(ws + (56ull << 20));     // 16 MB
    half_t* Vt   = (half_t*)(ws + (72ull << 20));     // 16 MB
    half_t* zh   = xh;

    cast_f32_f16<<<8192, 256, 0, stream>>>(x, xh, 8192 * 1024);
    transpose_cast<<<dim3(96, 32), dim3(32, 8), 0, stream>>>(W_qkv, Wqt, 1024, 3072);
    transpose_cast<<<dim3(32, 32), dim3(32, 8), 0, stream>>>(W_o, Wot, 1024, 1024);
    gemm_f16<1><<<dim3(64, 24), 256, 0, stream>>>(xh, Wqt, b_qkv, Vt, 8192, 3072, 1024,
                                                  wq, wk, Qh, Kh);
    attn<<<dim3(64, 8), 512, 0, stream>>>(Qh, Kh, Vt, zh);
    gemm_f16<0><<<dim3(64, 8), 256, 0, stream>>>(zh, Wot, b_o, out, 8192, 1024, 1024,
                                                 nullptr, nullptr, nullptr, nullptr);
}

// Round 9
// 268.959 us; speedup vs baseline: 1.0188x; 1.0130x over previous
//
#include <hip/hip_runtime.h>
#include <cmath>

typedef _Float16 half_t;
typedef _Float16 half8 __attribute__((ext_vector_type(8)));
typedef _Float16 half4v __attribute__((ext_vector_type(4)));
typedef float float4v __attribute__((ext_vector_type(4)));

#define LOG2E 1.44269504088896340736f

#define GLDS16(g, l)                                                                   \
    __builtin_amdgcn_global_load_lds((const __attribute__((address_space(1))) void*)(g), \
                                     (__attribute__((address_space(3))) void*)(l), 16, 0, 0)

// raw barriers: no compiler-inserted vmcnt(0) drain (the __syncthreads trap)
#define BAR_LGKM() __asm__ volatile("s_waitcnt lgkmcnt(0)\n\ts_barrier" ::: "memory")
#define BAR_VM(n)  __asm__ volatile("s_waitcnt vmcnt(" #n ")\n\ts_barrier" ::: "memory")

// ---------------- fused prep: cast x -> fp16, transpose+cast W_qkv and W_o ----------
// Three independent jobs (disjoint reads/writes), one launch instead of three:
//   blocks [0, 8192)        : cast x (8192*1024 fp32 -> fp16), 4 elem/thread
//   blocks [8192, 11264)    : transpose W_qkv [1024][3072] -> Wqt [3072][1024] fp16
//   blocks [11264, 12288)   : transpose W_o  [1024][1024] -> Wot [1024][1024] fp16
__global__ __launch_bounds__(256) void prep(
    const float* __restrict__ x,     half_t* __restrict__ xh,
    const float* __restrict__ Wqkv,  half_t* __restrict__ Wqt,
    const float* __restrict__ Wo,    half_t* __restrict__ Wot)
{
    __shared__ float tile[32][33];
    int bid = blockIdx.x, t = threadIdx.x;

    if (bid < 8192) {
        int i = (bid * 256 + t) * 4;
        float4 v = *(const float4*)(x + i);
        half4v o;
        o[0] = (half_t)v.x; o[1] = (half_t)v.y; o[2] = (half_t)v.z; o[3] = (half_t)v.w;
        *(half4v*)(xh + i) = o;
        return;
    }
    const float* in; half_t* out; int R, C, bx, by;
    if (bid < 11264) {
        int tb = bid - 8192;  in = Wqkv; out = Wqt; R = 1024; C = 3072;
        bx = tb % 96; by = tb / 96;
    } else {
        int tb = bid - 11264; in = Wo;   out = Wot; R = 1024; C = 1024;
        bx = tb % 32; by = tb / 32;
    }
    int tx = t & 31, ty = t >> 5;          // (32,8) flattened
    int c0 = bx * 32, r0 = by * 32;
    for (int p = 0; p < 4; p++) {
        int r = r0 + ty + p * 8;
        tile[ty + p * 8][tx] = in[(size_t)r * C + c0 + tx];
    }
    __syncthreads();
    for (int p = 0; p < 4; p++) {
        int c = c0 + ty + p * 8;
        out[(size_t)c * R + r0 + tx] = (half_t)tile[tx][ty + p * 8];
    }
}

// ---------------- GEMM: C[M][N] = A[M][K] * Bt[N][K]^T + bias ----------------
// r0 config RESTORED (best measured: 79.6 us, 647 TF): triple-buffered GLDS, raw
// barriers, bank-swizzle, 3 waves/SIMD. Seven rounds of alternatives (8-phase,
// 4-phase pipelined, 128x256 perfect packing, 4-block double-buffer) all lost to
// this multi-block overlap regime — do not touch without a within-run A/B.
template <int MODE>
__global__ __launch_bounds__(256, 3) void gemm_f16(
    const half_t* __restrict__ A,   // [M][K]
    const half_t* __restrict__ Bt,  // [N][K]
    const float* __restrict__ bias, // [N]
    void* __restrict__ Cout,
    int M, int N, int K,
    const float* __restrict__ wq, const float* __restrict__ wk,
    half_t* __restrict__ Qh, half_t* __restrict__ Kh)
{
    __shared__ __align__(16) half_t As[3][128 * 32];
    __shared__ __align__(16) half_t Bs[3][128 * 32];
    int t = threadIdx.x;
    int lane = t & 63, w = t >> 6;
    int m0 = blockIdx.x * 128, n0 = blockIdx.y * 128;
    int wm = (w >> 1) * 64, wn = (w & 1) * 64;
    int lrow = lane & 15, quad = lane >> 4;

    int lc = ((t & 3) - (t >> 3)) & 3;
    const half_t* gA = A  + (size_t)(m0 + (t >> 2)) * K + lc * 8;
    const half_t* gB = Bt + (size_t)(n0 + (t >> 2)) * K + lc * 8;
    half_t* ldsA[3] = { &As[0][w * 512], &As[1][w * 512], &As[2][w * 512] };
    half_t* ldsB[3] = { &Bs[0][w * 512], &Bs[1][w * 512], &Bs[2][w * 512] };

    int posq = (quad + (lrow >> 1)) & 3;

    float4v acc[4][4] = {};

    GLDS16(gA,                       ldsA[0]);
    GLDS16(gA + (size_t)64 * K,      ldsA[0] + 2048);
    GLDS16(gB,                       ldsB[0]);
    GLDS16(gB + (size_t)64 * K,      ldsB[0] + 2048);
    GLDS16(gA + 32,                  ldsA[1]);
    GLDS16(gA + (size_t)64 * K + 32, ldsA[1] + 2048);
    GLDS16(gB + 32,                  ldsB[1]);
    GLDS16(gB + (size_t)64 * K + 32, ldsB[1] + 2048);

    int nk = K >> 5;
    for (int ki = 0; ki < nk; ki++) {
        int cur = ki % 3, pre = (ki + 2) % 3;
        BAR_LGKM();
        if (ki + 2 < nk) {
            int kp = (ki + 2) << 5;
            GLDS16(gA + kp,                  ldsA[pre]);
            GLDS16(gA + (size_t)64 * K + kp, ldsA[pre] + 2048);
            GLDS16(gB + kp,                  ldsB[pre]);
            GLDS16(gB + (size_t)64 * K + kp, ldsB[pre] + 2048);
            BAR_VM(8);
        } else if (ki + 1 < nk) {
            BAR_VM(4);
        } else {
            BAR_VM(0);
        }
        half8 af[4], bf[4];
        for (int i = 0; i < 4; i++) af[i] = *(const half8*)(&As[cur][(wm + i * 16 + lrow) * 32 + posq * 8]);
        for (int i = 0; i < 4; i++) bf[i] = *(const half8*)(&Bs[cur][(wn + i * 16 + lrow) * 32 + posq * 8]);
        for (int mi = 0; mi < 4; mi++)
            for (int ni = 0; ni < 4; ni++)
                acc[mi][ni] = __builtin_amdgcn_mfma_f32_16x16x32_f16(af[mi], bf[ni], acc[mi][ni], 0, 0, 0);
    }

    if (MODE == 0) {
        float* out = (float*)Cout;
        for (int mi = 0; mi < 4; mi++)
            for (int ni = 0; ni < 4; ni++)
                for (int r = 0; r < 4; r++) {
                    int gr = m0 + wm + mi * 16 + quad * 4 + r;
                    int gc = n0 + wn + ni * 16 + lrow;
                    out[(size_t)gr * N + gc] = acc[mi][ni][r] + bias[gc];
                }
    } else {
        int nglob = n0 + wn;            // 64-aligned; one head per wave
        if (nglob < 2048) {
            int isK = nglob >> 10;
            int h = (nglob >> 6) & 15;
            const float* wv = isK ? wk : wq;
            half_t* dst = isK ? Kh : Qh;
            float post = isK ? 1.0f : LOG2E;   // pre-scale Q so attn works in log2 domain
            for (int mi = 0; mi < 4; mi++)
                for (int r = 0; r < 4; r++) {
                    int gr = m0 + wm + mi * 16 + quad * 4 + r;
                    float v[4]; float ss = 0.f;
                    for (int ni = 0; ni < 4; ni++) {
                        v[ni] = acc[mi][ni][r] + bias[nglob + ni * 16 + lrow];
                        ss += v[ni] * v[ni];
                    }
                    ss += __shfl_xor(ss, 1);
                    ss += __shfl_xor(ss, 2);
                    ss += __shfl_xor(ss, 4);
                    ss += __shfl_xor(ss, 8);
                    float rr = rsqrtf(ss * (1.0f / 64.0f) + 1e-6f) * post;
                    int bb = gr >> 11, s = gr & 2047;
                    size_t rowbase = ((size_t)((bb * 16 + h) * 2048 + s)) * 64;
                    for (int ni = 0; ni < 4; ni++) {
                        int d = ni * 16 + lrow;
                        dst[rowbase + d] = (half_t)(v[ni] * rr * wv[d]);
                    }
                }
        } else {
            // V part: store transposed into Vt[bh][d][s]
            half_t* Vt = (half_t*)Cout;
            for (int mi = 0; mi < 4; mi++) {
                int gr = m0 + wm + mi * 16 + quad * 4;   // s-base, 4-aligned
                int bb = gr >> 11, s = gr & 2047;
                for (int ni = 0; ni < 4; ni++) {
                    int dg = nglob + ni * 16 + lrow - 2048;   // 0..1023
                    float bv = bias[nglob + ni * 16 + lrow];
                    half4v oh;
                    for (int r = 0; r < 4; r++) oh[r] = (half_t)(acc[mi][ni][r] + bv);
                    *(half4v*)(Vt + ((size_t)((bb * 16 + (dg >> 6)) * 64 + (dg & 63))) * 2048 + s) = oh;
                }
            }
        }
    }
}

// ---------------- Flash attention, causal, no scale (Q pre-scaled by LOG2E) --
// 8 waves / 128 q-rows, paired q-tiles (i,15-i), grid (bh, pair) for XCD L2.
// r8: s_setprio(1) around the MFMA clusters (T5 — the measured-positive case is
// exactly this multi-wave non-lockstep attn structure, +4-7%).
__global__ __launch_bounds__(512, 4) void attn(
    const half_t* __restrict__ Qh, const half_t* __restrict__ Kh, const half_t* __restrict__ Vt,
    half_t* __restrict__ Z)
{
    __shared__ __align__(16) half_t Ks[2][128 * 64];  // [buf][key][d], pos = chunk ^ (key&7)
    __shared__ __align__(16) half_t Vs[2][64 * 128];  // [buf][d][key], pos = chunk ^ (d&7)
    __shared__ __align__(16) half_t Ps[8][16 * 64];   // per-wave [q][key-half]

    int bh = blockIdx.x;
    int b = bh >> 4, h = bh & 15;
    int t = threadIdx.x, lane = t & 63, w = t >> 6;
    int lrow = lane & 15, quad = lane >> 4;

    int scc = (lane & 7) ^ ((lane >> 3) & 7);
    const half_t* gK0 = Kh + ((size_t)bh * 2048 + w * 16 + (lane >> 3)) * 64 + scc * 8;
    int vr0 = w * 8 + (lane >> 4);
    int vc0 = (lane & 15) ^ (lane >> 4);
    int vc1 = (lane & 15) ^ ((lane >> 4) + 4);
    const half_t* gV0 = Vt + ((size_t)bh * 64 + vr0) * 2048 + vc0 * 8;
    const half_t* gV1 = Vt + ((size_t)bh * 64 + vr0 + 4) * 2048 + vc1 * 8;
    half_t* ldsK[2] = { &Ks[0][w * 1024], &Ks[1][w * 1024] };
    half_t* ldsV[2] = { &Vs[0][w * 1024], &Vs[1][w * 1024] };

    int sw = lrow & 7;
    int cA = (quad ^ sw) * 8;
    int cB = ((quad + 4) ^ sw) * 8;
    half_t* PsW = &Ps[w][lrow * 64];

    for (int pass = 0; pass < 2; pass++) {
        int qt = pass ? (15 - (int)blockIdx.y) : (int)blockIdx.y;
        int q0w = qt * 128 + w * 16;

        const half_t* Qbase = Qh + ((size_t)bh * 2048 + q0w + lrow) * 64;
        half8 qf0 = *(const half8*)(Qbase + quad * 8);
        half8 qf1 = *(const half8*)(Qbase + 32 + quad * 8);

        float4v ot[4] = {};
        float m = -__builtin_inff(), l = 0.f;

        int nt = qt + 1;
        __syncthreads();
        GLDS16(gK0,       ldsK[0]);
        GLDS16(gK0 + 512, ldsK[0] + 512);
        GLDS16(gV0,       ldsV[0]);
        GLDS16(gV1,       ldsV[0] + 512);

        for (int kt = 0; kt < nt; kt++) {
            int cur = kt & 1, nxt = cur ^ 1;
            int kb = kt * 128;
            BAR_LGKM();
            if (kt + 1 < nt) {
                size_t ko = (size_t)(kb + 128);
                GLDS16(gK0 + ko * 64,       ldsK[nxt]);
                GLDS16(gK0 + ko * 64 + 512, ldsK[nxt] + 512);
                GLDS16(gV0 + ko,            ldsV[nxt]);
                GLDS16(gV1 + ko,            ldsV[nxt] + 512);
                BAR_VM(4);
            } else {
                BAR_VM(0);
            }

            float4v st[8];
            __builtin_amdgcn_s_setprio(1);
            for (int f = 0; f < 8; f++) {
                float4v z = {};
                const half_t* kr = &Ks[cur][(f * 16 + lrow) * 64];
                half8 k0 = *(const half8*)(kr + cA);
                half8 k1 = *(const half8*)(kr + cB);
                z = __builtin_amdgcn_mfma_f32_16x16x32_f16(k0, qf0, z, 0, 0, 0);
                z = __builtin_amdgcn_mfma_f32_16x16x32_f16(k1, qf1, z, 0, 0, 0);
                st[f] = z;
            }
            __builtin_amdgcn_s_setprio(0);
            if (kb + 127 > q0w) {
                int qabs = q0w + lrow;
                for (int f = 0; f < 8; f++)
                    for (int r = 0; r < 4; r++) {
                        int key = kb + f * 16 + quad * 4 + r;
                        if (key > qabs) st[f][r] = -__builtin_inff();
                    }
            }
            float tm = st[0][0];
            for (int f = 0; f < 8; f++)
                for (int r = 0; r < 4; r++) tm = fmaxf(tm, st[f][r]);
            tm = fmaxf(tm, __shfl_xor(tm, 16));
            tm = fmaxf(tm, __shfl_xor(tm, 32));
            float mn = fmaxf(m, tm);
            float alpha = __builtin_amdgcn_exp2f(m - mn);
            m = mn;
            float rs = 0.f;
            uint2 pw1[4];
            for (int f = 0; f < 8; f++) {
                float p0 = __builtin_amdgcn_exp2f(st[f][0] - mn);
                float p1 = __builtin_amdgcn_exp2f(st[f][1] - mn);
                float p2 = __builtin_amdgcn_exp2f(st[f][2] - mn);
                float p3 = __builtin_amdgcn_exp2f(st[f][3] - mn);
                rs += (p0 + p1) + (p2 + p3);
                uint2 pw;
                pw.x = __builtin_bit_cast(unsigned, __builtin_amdgcn_cvt_pkrtz(p0, p1));
                pw.y = __builtin_bit_cast(unsigned, __builtin_amdgcn_cvt_pkrtz(p2, p3));
                if (f < 4) {
                    int cc = (2 * f + (quad >> 1)) ^ sw;
                    *(uint2*)(PsW + cc * 8 + (quad & 1) * 4) = pw;
                } else {
                    pw1[f - 4] = pw;
                }
            }
            rs += __shfl_xor(rs, 16);
            rs += __shfl_xor(rs, 32);
            l = l * alpha + rs;
            for (int f2 = 0; f2 < 4; f2++)
                for (int r = 0; r < 4; r++) ot[f2][r] *= alpha;

            __asm__ volatile("s_waitcnt lgkmcnt(0)" ::: "memory");
            half8 p0v = *(const half8*)(PsW + cA);
            half8 p1v = *(const half8*)(PsW + cB);
            __builtin_amdgcn_s_setprio(1);
            for (int f2 = 0; f2 < 4; f2++) {
                int row = f2 * 16 + lrow;
                half8 v0 = *(const half8*)(&Vs[cur][row * 128 + ((quad ^ sw)) * 8]);
                half8 v1 = *(const half8*)(&Vs[cur][row * 128 + (((4 + quad) ^ sw)) * 8]);
                ot[f2] = __builtin_amdgcn_mfma_f32_16x16x32_f16(v0, p0v, ot[f2], 0, 0, 0);
                ot[f2] = __builtin_amdgcn_mfma_f32_16x16x32_f16(v1, p1v, ot[f2], 0, 0, 0);
            }
            __builtin_amdgcn_s_setprio(0);
            for (int f = 0; f < 4; f++) {
                int cc = (2 * f + (quad >> 1)) ^ sw;
                *(uint2*)(PsW + cc * 8 + (quad & 1) * 4) = pw1[f];
            }
            __asm__ volatile("s_waitcnt lgkmcnt(0)" ::: "memory");
            half8 p2v = *(const half8*)(PsW + cA);
            half8 p3v = *(const half8*)(PsW + cB);
            __builtin_amdgcn_s_setprio(1);
            for (int f2 = 0; f2 < 4; f2++) {
                int row = f2 * 16 + lrow;
                half8 v2 = *(const half8*)(&Vs[cur][row * 128 + (((8 + quad) ^ sw)) * 8]);
                half8 v3 = *(const half8*)(&Vs[cur][row * 128 + (((12 + quad) ^ sw)) * 8]);
                ot[f2] = __builtin_amdgcn_mfma_f32_16x16x32_f16(v2, p2v, ot[f2], 0, 0, 0);
                ot[f2] = __builtin_amdgcn_mfma_f32_16x16x32_f16(v3, p3v, ot[f2], 0, 0, 0);
            }
            __builtin_amdgcn_s_setprio(0);
        }

        float inv = 1.0f / l;
        size_t base = ((size_t)(b * 2048) + q0w + lrow) * 1024 + h * 64;
        for (int f2 = 0; f2 < 4; f2++) {
            half4v oh;
            for (int r = 0; r < 4; r++) oh[r] = (half_t)(ot[f2][r] * inv);
            *(half4v*)(Z + base + f2 * 16 + quad * 4) = oh;
        }
    }
}

// ---------------- launch ----------------
extern "C" void kernel_launch(void* const* d_in, const int* in_sizes, int n_in,
                              void* d_out, int out_size, void* d_ws, size_t ws_size,
                              hipStream_t stream)
{
    const float* x     = (const float*)d_in[0];
    // d_in[1] = mask (causal, known analytically) - unused
    const float* W_qkv = (const float*)d_in[2];
    const float* b_qkv = (const float*)d_in[3];
    const float* W_o   = (const float*)d_in[4];
    const float* b_o   = (const float*)d_in[5];
    const float* wq    = (const float*)d_in[6];
    const float* wk    = (const float*)d_in[7];
    float* out = (float*)d_out;

    char* ws = (char*)d_ws;
    half_t* xh   = (half_t*)(ws);                     // 16 MB (reused as zh after attn)
    half_t* Wqt  = (half_t*)(ws + (16ull << 20));     // 6 MB
    half_t* Wot  = (half_t*)(ws + (22ull << 20));     // 2 MB
    half_t* Qh   = (half_t*)(ws + (40ull << 20));     // 16 MB
    half_t* Kh   = (half_t*)(ws + (56ull << 20));     // 16 MB
    half_t* Vt   = (half_t*)(ws + (72ull << 20));     // 16 MB
    half_t* zh   = xh;

    prep<<<12288, 256, 0, stream>>>(x, xh, W_qkv, Wqt, W_o, Wot);
    gemm_f16<1><<<dim3(64, 24), 256, 0, stream>>>(xh, Wqt, b_qkv, Vt, 8192, 3072, 1024,
                                                  wq, wk, Qh, Kh);
    attn<<<dim3(64, 8), 512, 0, stream>>>(Qh, Kh, Vt, zh);
    gemm_f16<0><<<dim3(64, 8), 256, 0, stream>>>(zh, Wot, b_o, out, 8192, 1024, 1024,
                                                 nullptr, nullptr, nullptr, nullptr);
}

// Round 10
// 264.759 us; speedup vs baseline: 1.0350x; 1.0159x over previous
//
#include <hip/hip_runtime.h>
#include <cmath>

typedef _Float16 half_t;
typedef _Float16 half8 __attribute__((ext_vector_type(8)));
typedef _Float16 half4v __attribute__((ext_vector_type(4)));
typedef float float4v __attribute__((ext_vector_type(4)));

#define LOG2E 1.44269504088896340736f

#define GLDS16(g, l)                                                                   \
    __builtin_amdgcn_global_load_lds((const __attribute__((address_space(1))) void*)(g), \
                                     (__attribute__((address_space(3))) void*)(l), 16, 0, 0)

// raw barriers: no compiler-inserted vmcnt(0) drain (the __syncthreads trap)
#define BAR_LGKM() __asm__ volatile("s_waitcnt lgkmcnt(0)\n\ts_barrier" ::: "memory")
#define BAR_VM(n)  __asm__ volatile("s_waitcnt vmcnt(" #n ")\n\ts_barrier" ::: "memory")

// ---------------- fused prep: cast x -> fp16, transpose+cast W_qkv and W_o ----------
//   blocks [0, 8192)        : cast x (8192*1024 fp32 -> fp16), 4 elem/thread
//   blocks [8192, 11264)    : transpose W_qkv [1024][3072] -> Wqt [3072][1024] fp16
//   blocks [11264, 12288)   : transpose W_o  [1024][1024] -> Wot [1024][1024] fp16
__global__ __launch_bounds__(256) void prep(
    const float* __restrict__ x,     half_t* __restrict__ xh,
    const float* __restrict__ Wqkv,  half_t* __restrict__ Wqt,
    const float* __restrict__ Wo,    half_t* __restrict__ Wot)
{
    __shared__ float tile[32][33];
    int bid = blockIdx.x, t = threadIdx.x;

    if (bid < 8192) {
        int i = (bid * 256 + t) * 4;
        float4 v = *(const float4*)(x + i);
        half4v o;
        o[0] = (half_t)v.x; o[1] = (half_t)v.y; o[2] = (half_t)v.z; o[3] = (half_t)v.w;
        *(half4v*)(xh + i) = o;
        return;
    }
    const float* in; half_t* out; int R, C, bx, by;
    if (bid < 11264) {
        int tb = bid - 8192;  in = Wqkv; out = Wqt; R = 1024; C = 3072;
        bx = tb % 96; by = tb / 96;
    } else {
        int tb = bid - 11264; in = Wo;   out = Wot; R = 1024; C = 1024;
        bx = tb % 32; by = tb / 32;
    }
    int tx = t & 31, ty = t >> 5;          // (32,8) flattened
    int c0 = bx * 32, r0 = by * 32;
    for (int p = 0; p < 4; p++) {
        int r = r0 + ty + p * 8;
        tile[ty + p * 8][tx] = in[(size_t)r * C + c0 + tx];
    }
    __syncthreads();
    for (int p = 0; p < 4; p++) {
        int c = c0 + ty + p * 8;
        out[(size_t)c * R + r0 + tx] = (half_t)tile[tx][ty + p * 8];
    }
}

// ---------------- GEMM: C[M][N] = A[M][K] * Bt[N][K]^T + bias ----------------
// r0 config (best measured: ~78 us, ~660 TF): triple-buffered GLDS, raw barriers,
// bank-swizzle, 3 waves/SIMD. Seven rounds of alternatives all lost to this
// multi-block overlap regime — frozen.
template <int MODE>
__global__ __launch_bounds__(256, 3) void gemm_f16(
    const half_t* __restrict__ A,   // [M][K]
    const half_t* __restrict__ Bt,  // [N][K]
    const float* __restrict__ bias, // [N]
    void* __restrict__ Cout,
    int M, int N, int K,
    const float* __restrict__ wq, const float* __restrict__ wk,
    half_t* __restrict__ Qh, half_t* __restrict__ Kh)
{
    __shared__ __align__(16) half_t As[3][128 * 32];
    __shared__ __align__(16) half_t Bs[3][128 * 32];
    int t = threadIdx.x;
    int lane = t & 63, w = t >> 6;
    int m0 = blockIdx.x * 128, n0 = blockIdx.y * 128;
    int wm = (w >> 1) * 64, wn = (w & 1) * 64;
    int lrow = lane & 15, quad = lane >> 4;

    int lc = ((t & 3) - (t >> 3)) & 3;
    const half_t* gA = A  + (size_t)(m0 + (t >> 2)) * K + lc * 8;
    const half_t* gB = Bt + (size_t)(n0 + (t >> 2)) * K + lc * 8;
    half_t* ldsA[3] = { &As[0][w * 512], &As[1][w * 512], &As[2][w * 512] };
    half_t* ldsB[3] = { &Bs[0][w * 512], &Bs[1][w * 512], &Bs[2][w * 512] };

    int posq = (quad + (lrow >> 1)) & 3;

    float4v acc[4][4] = {};

    GLDS16(gA,                       ldsA[0]);
    GLDS16(gA + (size_t)64 * K,      ldsA[0] + 2048);
    GLDS16(gB,                       ldsB[0]);
    GLDS16(gB + (size_t)64 * K,      ldsB[0] + 2048);
    GLDS16(gA + 32,                  ldsA[1]);
    GLDS16(gA + (size_t)64 * K + 32, ldsA[1] + 2048);
    GLDS16(gB + 32,                  ldsB[1]);
    GLDS16(gB + (size_t)64 * K + 32, ldsB[1] + 2048);

    int nk = K >> 5;
    for (int ki = 0; ki < nk; ki++) {
        int cur = ki % 3, pre = (ki + 2) % 3;
        BAR_LGKM();
        if (ki + 2 < nk) {
            int kp = (ki + 2) << 5;
            GLDS16(gA + kp,                  ldsA[pre]);
            GLDS16(gA + (size_t)64 * K + kp, ldsA[pre] + 2048);
            GLDS16(gB + kp,                  ldsB[pre]);
            GLDS16(gB + (size_t)64 * K + kp, ldsB[pre] + 2048);
            BAR_VM(8);
        } else if (ki + 1 < nk) {
            BAR_VM(4);
        } else {
            BAR_VM(0);
        }
        half8 af[4], bf[4];
        for (int i = 0; i < 4; i++) af[i] = *(const half8*)(&As[cur][(wm + i * 16 + lrow) * 32 + posq * 8]);
        for (int i = 0; i < 4; i++) bf[i] = *(const half8*)(&Bs[cur][(wn + i * 16 + lrow) * 32 + posq * 8]);
        for (int mi = 0; mi < 4; mi++)
            for (int ni = 0; ni < 4; ni++)
                acc[mi][ni] = __builtin_amdgcn_mfma_f32_16x16x32_f16(af[mi], bf[ni], acc[mi][ni], 0, 0, 0);
    }

    if (MODE == 0) {
        float* out = (float*)Cout;
        for (int mi = 0; mi < 4; mi++)
            for (int ni = 0; ni < 4; ni++)
                for (int r = 0; r < 4; r++) {
                    int gr = m0 + wm + mi * 16 + quad * 4 + r;
                    int gc = n0 + wn + ni * 16 + lrow;
                    out[(size_t)gr * N + gc] = acc[mi][ni][r] + bias[gc];
                }
    } else {
        int nglob = n0 + wn;            // 64-aligned; one head per wave
        if (nglob < 2048) {
            int isK = nglob >> 10;
            int h = (nglob >> 6) & 15;
            const float* wv = isK ? wk : wq;
            half_t* dst = isK ? Kh : Qh;
            float post = isK ? 1.0f : LOG2E;   // pre-scale Q so attn works in log2 domain
            for (int mi = 0; mi < 4; mi++)
                for (int r = 0; r < 4; r++) {
                    int gr = m0 + wm + mi * 16 + quad * 4 + r;
                    float v[4]; float ss = 0.f;
                    for (int ni = 0; ni < 4; ni++) {
                        v[ni] = acc[mi][ni][r] + bias[nglob + ni * 16 + lrow];
                        ss += v[ni] * v[ni];
                    }
                    ss += __shfl_xor(ss, 1);
                    ss += __shfl_xor(ss, 2);
                    ss += __shfl_xor(ss, 4);
                    ss += __shfl_xor(ss, 8);
                    float rr = rsqrtf(ss * (1.0f / 64.0f) + 1e-6f) * post;
                    int bb = gr >> 11, s = gr & 2047;
                    size_t rowbase = ((size_t)((bb * 16 + h) * 2048 + s)) * 64;
                    for (int ni = 0; ni < 4; ni++) {
                        int d = ni * 16 + lrow;
                        dst[rowbase + d] = (half_t)(v[ni] * rr * wv[d]);
                    }
                }
        } else {
            // V part: store transposed into Vt[bh][d][s]
            half_t* Vt = (half_t*)Cout;
            for (int mi = 0; mi < 4; mi++) {
                int gr = m0 + wm + mi * 16 + quad * 4;   // s-base, 4-aligned
                int bb = gr >> 11, s = gr & 2047;
                for (int ni = 0; ni < 4; ni++) {
                    int dg = nglob + ni * 16 + lrow - 2048;   // 0..1023
                    float bv = bias[nglob + ni * 16 + lrow];
                    half4v oh;
                    for (int r = 0; r < 4; r++) oh[r] = (half_t)(acc[mi][ni][r] + bv);
                    *(half4v*)(Vt + ((size_t)((bb * 16 + (dg >> 6)) * 64 + (dg & 63))) * 2048 + s) = oh;
                }
            }
        }
    }
}

// ---------------- Flash attention, causal, no scale (Q pre-scaled by LOG2E) --
// 8 waves / 128 q-rows, paired q-tiles (i,15-i), grid (bh, pair) for XCD L2.
// r8: s_setprio(1) around MFMA clusters (T5). r10: defer-max (T13) — skip the
// O/l rescale when the wave's tile-max stays within 8 (log2 units) of the
// running max; P then bounded by 2^8=256 (fp16-safe), final ot/l scale-invariant.
__global__ __launch_bounds__(512, 4) void attn(
    const half_t* __restrict__ Qh, const half_t* __restrict__ Kh, const half_t* __restrict__ Vt,
    half_t* __restrict__ Z)
{
    __shared__ __align__(16) half_t Ks[2][128 * 64];  // [buf][key][d], pos = chunk ^ (key&7)
    __shared__ __align__(16) half_t Vs[2][64 * 128];  // [buf][d][key], pos = chunk ^ (d&7)
    __shared__ __align__(16) half_t Ps[8][16 * 64];   // per-wave [q][key-half]

    int bh = blockIdx.x;
    int b = bh >> 4, h = bh & 15;
    int t = threadIdx.x, lane = t & 63, w = t >> 6;
    int lrow = lane & 15, quad = lane >> 4;

    int scc = (lane & 7) ^ ((lane >> 3) & 7);
    const half_t* gK0 = Kh + ((size_t)bh * 2048 + w * 16 + (lane >> 3)) * 64 + scc * 8;
    int vr0 = w * 8 + (lane >> 4);
    int vc0 = (lane & 15) ^ (lane >> 4);
    int vc1 = (lane & 15) ^ ((lane >> 4) + 4);
    const half_t* gV0 = Vt + ((size_t)bh * 64 + vr0) * 2048 + vc0 * 8;
    const half_t* gV1 = Vt + ((size_t)bh * 64 + vr0 + 4) * 2048 + vc1 * 8;
    half_t* ldsK[2] = { &Ks[0][w * 1024], &Ks[1][w * 1024] };
    half_t* ldsV[2] = { &Vs[0][w * 1024], &Vs[1][w * 1024] };

    int sw = lrow & 7;
    int cA = (quad ^ sw) * 8;
    int cB = ((quad + 4) ^ sw) * 8;
    half_t* PsW = &Ps[w][lrow * 64];

    for (int pass = 0; pass < 2; pass++) {
        int qt = pass ? (15 - (int)blockIdx.y) : (int)blockIdx.y;
        int q0w = qt * 128 + w * 16;

        const half_t* Qbase = Qh + ((size_t)bh * 2048 + q0w + lrow) * 64;
        half8 qf0 = *(const half8*)(Qbase + quad * 8);
        half8 qf1 = *(const half8*)(Qbase + 32 + quad * 8);

        float4v ot[4] = {};
        float m = -__builtin_inff(), l = 0.f;

        int nt = qt + 1;
        __syncthreads();
        GLDS16(gK0,       ldsK[0]);
        GLDS16(gK0 + 512, ldsK[0] + 512);
        GLDS16(gV0,       ldsV[0]);
        GLDS16(gV1,       ldsV[0] + 512);

        for (int kt = 0; kt < nt; kt++) {
            int cur = kt & 1, nxt = cur ^ 1;
            int kb = kt * 128;
            BAR_LGKM();
            if (kt + 1 < nt) {
                size_t ko = (size_t)(kb + 128);
                GLDS16(gK0 + ko * 64,       ldsK[nxt]);
                GLDS16(gK0 + ko * 64 + 512, ldsK[nxt] + 512);
                GLDS16(gV0 + ko,            ldsV[nxt]);
                GLDS16(gV1 + ko,            ldsV[nxt] + 512);
                BAR_VM(4);
            } else {
                BAR_VM(0);
            }

            float4v st[8];
            __builtin_amdgcn_s_setprio(1);
            for (int f = 0; f < 8; f++) {
                float4v z = {};
                const half_t* kr = &Ks[cur][(f * 16 + lrow) * 64];
                half8 k0 = *(const half8*)(kr + cA);
                half8 k1 = *(const half8*)(kr + cB);
                z = __builtin_amdgcn_mfma_f32_16x16x32_f16(k0, qf0, z, 0, 0, 0);
                z = __builtin_amdgcn_mfma_f32_16x16x32_f16(k1, qf1, z, 0, 0, 0);
                st[f] = z;
            }
            __builtin_amdgcn_s_setprio(0);
            if (kb + 127 > q0w) {
                int qabs = q0w + lrow;
                for (int f = 0; f < 8; f++)
                    for (int r = 0; r < 4; r++) {
                        int key = kb + f * 16 + quad * 4 + r;
                        if (key > qabs) st[f][r] = -__builtin_inff();
                    }
            }
            float tm = st[0][0];
            for (int f = 0; f < 8; f++)
                for (int r = 0; r < 4; r++) tm = fmaxf(tm, st[f][r]);
            tm = fmaxf(tm, __shfl_xor(tm, 16));
            tm = fmaxf(tm, __shfl_xor(tm, 32));
            // defer-max (T13): rescale only when the tile max meaningfully raises m
            if (!__all(tm <= m + 8.0f)) {
                float mn = fmaxf(m, tm);
                float alpha = __builtin_amdgcn_exp2f(m - mn);
                m = mn;
                l *= alpha;
                for (int f2 = 0; f2 < 4; f2++)
                    for (int r = 0; r < 4; r++) ot[f2][r] *= alpha;
            }
            float rs = 0.f;
            uint2 pw1[4];
            for (int f = 0; f < 8; f++) {
                float p0 = __builtin_amdgcn_exp2f(st[f][0] - m);
                float p1 = __builtin_amdgcn_exp2f(st[f][1] - m);
                float p2 = __builtin_amdgcn_exp2f(st[f][2] - m);
                float p3 = __builtin_amdgcn_exp2f(st[f][3] - m);
                rs += (p0 + p1) + (p2 + p3);
                uint2 pw;
                pw.x = __builtin_bit_cast(unsigned, __builtin_amdgcn_cvt_pkrtz(p0, p1));
                pw.y = __builtin_bit_cast(unsigned, __builtin_amdgcn_cvt_pkrtz(p2, p3));
                if (f < 4) {
                    int cc = (2 * f + (quad >> 1)) ^ sw;
                    *(uint2*)(PsW + cc * 8 + (quad & 1) * 4) = pw;
                } else {
                    pw1[f - 4] = pw;
                }
            }
            rs += __shfl_xor(rs, 16);
            rs += __shfl_xor(rs, 32);
            l += rs;

            __asm__ volatile("s_waitcnt lgkmcnt(0)" ::: "memory");
            half8 p0v = *(const half8*)(PsW + cA);
            half8 p1v = *(const half8*)(PsW + cB);
            __builtin_amdgcn_s_setprio(1);
            for (int f2 = 0; f2 < 4; f2++) {
                int row = f2 * 16 + lrow;
                half8 v0 = *(const half8*)(&Vs[cur][row * 128 + ((quad ^ sw)) * 8]);
                half8 v1 = *(const half8*)(&Vs[cur][row * 128 + (((4 + quad) ^ sw)) * 8]);
                ot[f2] = __builtin_amdgcn_mfma_f32_16x16x32_f16(v0, p0v, ot[f2], 0, 0, 0);
                ot[f2] = __builtin_amdgcn_mfma_f32_16x16x32_f16(v1, p1v, ot[f2], 0, 0, 0);
            }
            __builtin_amdgcn_s_setprio(0);
            for (int f = 0; f < 4; f++) {
                int cc = (2 * f + (quad >> 1)) ^ sw;
                *(uint2*)(PsW + cc * 8 + (quad & 1) * 4) = pw1[f];
            }
            __asm__ volatile("s_waitcnt lgkmcnt(0)" ::: "memory");
            half8 p2v = *(const half8*)(PsW + cA);
            half8 p3v = *(const half8*)(PsW + cB);
            __builtin_amdgcn_s_setprio(1);
            for (int f2 = 0; f2 < 4; f2++) {
                int row = f2 * 16 + lrow;
                half8 v2 = *(const half8*)(&Vs[cur][row * 128 + (((8 + quad) ^ sw)) * 8]);
                half8 v3 = *(const half8*)(&Vs[cur][row * 128 + (((12 + quad) ^ sw)) * 8]);
                ot[f2] = __builtin_amdgcn_mfma_f32_16x16x32_f16(v2, p2v, ot[f2], 0, 0, 0);
                ot[f2] = __builtin_amdgcn_mfma_f32_16x16x32_f16(v3, p3v, ot[f2], 0, 0, 0);
            }
            __builtin_amdgcn_s_setprio(0);
        }

        float inv = 1.0f / l;
        size_t base = ((size_t)(b * 2048) + q0w + lrow) * 1024 + h * 64;
        for (int f2 = 0; f2 < 4; f2++) {
            half4v oh;
            for (int r = 0; r < 4; r++) oh[r] = (half_t)(ot[f2][r] * inv);
            *(half4v*)(Z + base + f2 * 16 + quad * 4) = oh;
        }
    }
}

// ---------------- launch ----------------
extern "C" void kernel_launch(void* const* d_in, const int* in_sizes, int n_in,
                              void* d_out, int out_size, void* d_ws, size_t ws_size,
                              hipStream_t stream)
{
    const float* x     = (const float*)d_in[0];
    // d_in[1] = mask (causal, known analytically) - unused
    const float* W_qkv = (const float*)d_in[2];
    const float* b_qkv = (const float*)d_in[3];
    const float* W_o   = (const float*)d_in[4];
    const float* b_o   = (const float*)d_in[5];
    const float* wq    = (const float*)d_in[6];
    const float* wk    = (const float*)d_in[7];
    float* out = (float*)d_out;

    char* ws = (char*)d_ws;
    half_t* xh   = (half_t*)(ws);                     // 16 MB (reused as zh after attn)
    half_t* Wqt  = (half_t*)(ws + (16ull << 20));     // 6 MB
    half_t* Wot  = (half_t*)(ws + (22ull << 20));     // 2 MB
    half_t* Qh   = (half_t*)(ws + (40ull << 20));     // 16 MB
    half_t* Kh   = (half_t*)(ws + (56ull << 20));     // 16 MB
    half_t* Vt   = (half_t*)(ws + (72ull << 20));     // 16 MB
    half_t* zh   = xh;

    prep<<<12288, 256, 0, stream>>>(x, xh, W_qkv, Wqt, W_o, Wot);
    gemm_f16<1><<<dim3(64, 24), 256, 0, stream>>>(xh, Wqt, b_qkv, Vt, 8192, 3072, 1024,
                                                  wq, wk, Qh, Kh);
    attn<<<dim3(64, 8), 512, 0, stream>>>(Qh, Kh, Vt, zh);
    gemm_f16<0><<<dim3(64, 8), 256, 0, stream>>>(zh, Wot, b_o, out, 8192, 1024, 1024,
                                                 nullptr, nullptr, nullptr, nullptr);
}